// Round 1
// baseline (995.564 us; speedup 1.0000x reference)
//
#include <hip/hip_runtime.h>
#include <cstdint>
#include <cstddef>

// Extractor_N2V: out = BN(seg_mean(x) + eps1*x) @ W2^T + b2, x = h@W1^T + b1
// Folded form:  g = seg_sum(h[src],dst)/deg + eps1*h   [N,128]
//               x = g@W1^T + b''   (b'' = (1+eps1) b1)
//               stats from mean(g) and S2 = G^T G analytically
//               out = g @ M^T + c, M = W2 diag(s) W1  [256,128]

#define IN_DIM 128
#define H_DIM 256

static inline size_t align256(size_t x){ return (x + 255) & ~(size_t)255; }

__global__ void k_count(const int* __restrict__ dst, int* __restrict__ deg, int E_) {
  int i = blockIdx.x*blockDim.x + threadIdx.x;
  int stride = gridDim.x*blockDim.x;
  for (; i < E_; i += stride) atomicAdd(&deg[dst[i]], 1);
}

__global__ void k_scan1(const int* __restrict__ deg, int* __restrict__ part, int N_) {
  __shared__ int sh[256];
  int t = threadIdx.x, gi = blockIdx.x*256 + t;
  sh[t] = (gi < N_) ? deg[gi] : 0;
  __syncthreads();
  for (int off=128; off>0; off>>=1){ if (t<off) sh[t]+=sh[t+off]; __syncthreads(); }
  if (t==0) part[blockIdx.x] = sh[0];
}

__global__ void k_scan2(const int* __restrict__ part, int* __restrict__ partScan,
                        int nblk, int* __restrict__ row_ptr, int N_, int E_) {
  __shared__ int sh[512];
  int t = threadIdx.x;
  sh[t] = (t < nblk) ? part[t] : 0;
  __syncthreads();
  if (t==0){
    int run=0;
    for (int i=0;i<nblk;i++){ int v=sh[i]; sh[i]=run; run+=v; }
    row_ptr[N_] = E_;
  }
  __syncthreads();
  if (t < nblk) partScan[t] = sh[t];
}

__global__ void k_scan3(const int* __restrict__ deg, const int* __restrict__ partScan,
                        int* __restrict__ row_ptr, int* __restrict__ cursor, int N_) {
  __shared__ int sh[256];
  int t = threadIdx.x, gi = blockIdx.x*256 + t;
  int v = (gi < N_) ? deg[gi] : 0;
  sh[t] = v; __syncthreads();
  for (int off=1; off<256; off<<=1){
    int add = (t>=off) ? sh[t-off] : 0;
    __syncthreads();
    sh[t] += add;
    __syncthreads();
  }
  if (gi < N_){
    int ex = partScan[blockIdx.x] + sh[t] - v;   // exclusive prefix
    row_ptr[gi] = ex; cursor[gi] = ex;
  }
}

__global__ void k_fill(const int* __restrict__ src, const int* __restrict__ dst,
                       int* __restrict__ cursor, int* __restrict__ eidx, int E_) {
  int i = blockIdx.x*blockDim.x + threadIdx.x;
  int stride = gridDim.x*blockDim.x;
  for (; i < E_; i += stride){
    int d = dst[i];
    int p = atomicAdd(&cursor[d], 1);
    eidx[p] = src[i];
  }
}

// one wave per node; lane owns 2 features (float2). Reads h rows of in-neighbors.
__global__ __launch_bounds__(256) void k_gather(const float* __restrict__ h,
                        const int* __restrict__ row_ptr, const int* __restrict__ eidx,
                        const float* __restrict__ eps1, float* __restrict__ g, int N_) {
  int w = (int)((blockIdx.x*blockDim.x + threadIdx.x) >> 6);
  int lane = threadIdx.x & 63;
  if (w >= N_) return;
  int beg = row_ptr[w], end = row_ptr[w+1];
  const float2* h2 = (const float2*)h;
  float2 a0 = {0.f,0.f}, a1 = {0.f,0.f};
  int e = beg;
  for (; e+1 < end; e += 2){
    int s0 = eidx[e], s1 = eidx[e+1];
    float2 v0 = h2[(size_t)s0*64 + lane];
    float2 v1 = h2[(size_t)s1*64 + lane];
    a0.x += v0.x; a0.y += v0.y;
    a1.x += v1.x; a1.y += v1.y;
  }
  if (e < end){
    int s0 = eidx[e];
    float2 v0 = h2[(size_t)s0*64 + lane];
    a0.x += v0.x; a0.y += v0.y;
  }
  float degf = (float)(end - beg);
  float e1 = eps1[0];
  float2 hv = h2[(size_t)w*64 + lane];
  float2 o;
  o.x = (a0.x + a1.x)/degf + e1*hv.x;   // deg==0 -> NaN, matches reference 0/0
  o.y = (a0.y + a1.y)/degf + e1*hv.y;
  ((float2*)g)[(size_t)w*64 + lane] = o;
}

// S2 = G^T G (128x128) and colsum(g) via block-local register tiles + one atomic pass
__global__ __launch_bounds__(256) void k_gram(const float* __restrict__ g,
                       float* __restrict__ S2, float* __restrict__ colsum, int N_) {
  __shared__ float gs[64][129];
  int t = threadIdx.x;
  int tx = t & 15, ty = t >> 4;           // C rows: tx+16u, C cols: ty+16v
  float acc[8][8];
  #pragma unroll
  for (int u=0;u<8;u++)
    #pragma unroll
    for (int v=0;v<8;v++) acc[u][v]=0.f;
  float cs = 0.f;
  for (int r0 = blockIdx.x*64; r0 < N_; r0 += gridDim.x*64){
    __syncthreads();
    for (int idx = t; idx < 64*32; idx += 256){
      int r = idx >> 5, p = idx & 31;
      float4 v = {0.f,0.f,0.f,0.f};
      if (r0 + r < N_) v = ((const float4*)g)[(size_t)(r0+r)*32 + p];
      gs[r][p*4+0]=v.x; gs[r][p*4+1]=v.y; gs[r][p*4+2]=v.z; gs[r][p*4+3]=v.w;
    }
    __syncthreads();
    #pragma unroll 4
    for (int r=0;r<64;r++){
      float a[8], b[8];
      #pragma unroll
      for (int u=0;u<8;u++){ a[u]=gs[r][tx+16*u]; b[u]=gs[r][ty+16*u]; }
      #pragma unroll
      for (int u=0;u<8;u++)
        #pragma unroll
        for (int v=0;v<8;v++) acc[u][v] += a[u]*b[v];
    }
    if (t < 128){
      float c2=0.f;
      #pragma unroll 4
      for (int r=0;r<64;r++) c2 += gs[r][t];
      cs += c2;
    }
  }
  #pragma unroll
  for (int u=0;u<8;u++)
    #pragma unroll
    for (int v=0;v<8;v++)
      atomicAdd(&S2[(tx+16*u)*128 + (ty+16*v)], acc[u][v]);
  if (t < 128) atomicAdd(&colsum[t], cs);
}

// q[j] = w_j S2 w_j^T  (S2 symmetric -> column access is coalesced)
__global__ void k_quad(const float* __restrict__ W1, const float* __restrict__ S2,
                       float* __restrict__ qbuf) {
  __shared__ float ws[128];
  __shared__ float red[128];
  int j = blockIdx.x, d = threadIdx.x;
  ws[d] = W1[(size_t)j*128 + d];
  __syncthreads();
  float r = 0.f;
  for (int dp=0; dp<128; dp++) r += S2[dp*128 + d]*ws[dp];
  red[d] = r*ws[d];
  __syncthreads();
  for (int off=64; off>0; off>>=1){ if (d<off) red[d]+=red[d+off]; __syncthreads(); }
  if (d==0) qbuf[j] = red[0];
}

// per-channel stats -> s (scale), and c (fused output bias)
__global__ void k_stats2(const float* __restrict__ W1, const float* __restrict__ b1,
                         const float* __restrict__ W2, const float* __restrict__ b2,
                         const float* __restrict__ gamma, const float* __restrict__ beta,
                         const float* __restrict__ eps1, const float* __restrict__ colsum,
                         const float* __restrict__ qbuf, float* __restrict__ sbuf,
                         float* __restrict__ cbuf, int N_) {
  __shared__ float mg[128];
  __shared__ float tt[256];
  int t = threadIdx.x;
  float invN = 1.f/(float)N_;
  if (t < 128) mg[t] = colsum[t]*invN;
  __syncthreads();
  float e1 = eps1[0];
  float bpp = (1.f + e1)*b1[t];
  const float* w = W1 + (size_t)t*128;
  float mx = bpp;
  for (int d=0; d<128; d++) mx += w[d]*mg[d];
  float ex2 = qbuf[t]*invN + 2.f*bpp*(mx - bpp) + bpp*bpp;
  float var = ex2 - mx*mx;
  float s = gamma[t]*rsqrtf(var + 1e-5f);
  sbuf[t] = s;
  tt[t] = (bpp - mx)*s + beta[t];
  __syncthreads();
  float c = b2[t];
  for (int j=0;j<256;j++) c += tt[j]*W2[(size_t)t*256 + j];
  cbuf[t] = c;
}

// M[k,d] = sum_j W2[k,j] * s[j] * W1[j,d]
__global__ void k_matM(const float* __restrict__ W1, const float* __restrict__ W2,
                       const float* __restrict__ sbuf, float* __restrict__ Mm) {
  __shared__ float ws[256];
  int k = blockIdx.x, d = threadIdx.x;   // 128 threads
  ws[d]       = W2[(size_t)k*256 + d]       * sbuf[d];
  ws[d + 128] = W2[(size_t)k*256 + d + 128] * sbuf[d + 128];
  __syncthreads();
  float acc = 0.f;
  for (int j=0;j<256;j++) acc += ws[j]*W1[(size_t)j*128 + d];  // coalesced over d
  Mm[(size_t)k*128 + d] = acc;
}

// out[i,k] = g[i,:] . M[k,:] + c[k]   tile 64 rows x 256 cols, K chunked by 32
__global__ __launch_bounds__(256) void k_out(const float* __restrict__ g, const float* __restrict__ Mm,
                     const float* __restrict__ cb, float* __restrict__ out, int N_) {
  __shared__ float gs[64][33];
  __shared__ float Ms[256][33];
  int t = threadIdx.x;
  int tx = t & 15, ty = t >> 4;   // thread: rows tx*4..+3, cols ty*16..+15
  int i0 = blockIdx.x*64;
  float acc[4][16];
  #pragma unroll
  for (int r=0;r<4;r++)
    #pragma unroll
    for (int q=0;q<16;q++) acc[r][q]=0.f;
  for (int ch=0; ch<4; ch++){
    __syncthreads();
    #pragma unroll
    for (int l=0;l<2;l++){
      int idx = t + l*256;
      int r = idx >> 3, p = idx & 7;
      float4 v = {0.f,0.f,0.f,0.f};
      if (i0 + r < N_) v = *(const float4*)&g[(size_t)(i0+r)*128 + ch*32 + p*4];
      gs[r][p*4+0]=v.x; gs[r][p*4+1]=v.y; gs[r][p*4+2]=v.z; gs[r][p*4+3]=v.w;
    }
    #pragma unroll
    for (int l=0;l<8;l++){
      int idx = t + l*256;
      int q = idx >> 3, p = idx & 7;
      float4 v = *(const float4*)&Mm[(size_t)q*128 + ch*32 + p*4];
      Ms[q][p*4+0]=v.x; Ms[q][p*4+1]=v.y; Ms[q][p*4+2]=v.z; Ms[q][p*4+3]=v.w;
    }
    __syncthreads();
    #pragma unroll 4
    for (int dd=0; dd<32; dd++){
      float a[4], b[16];
      #pragma unroll
      for (int r=0;r<4;r++) a[r] = gs[tx*4+r][dd];
      #pragma unroll
      for (int q=0;q<16;q++) b[q] = Ms[ty*16+q][dd];
      #pragma unroll
      for (int r=0;r<4;r++)
        #pragma unroll
        for (int q=0;q<16;q++) acc[r][q] += a[r]*b[q];
    }
  }
  float cv[16];
  #pragma unroll
  for (int q=0;q<16;q++) cv[q] = cb[ty*16+q];
  #pragma unroll
  for (int r=0;r<4;r++){
    int i = i0 + tx*4 + r;
    if (i < N_){
      #pragma unroll
      for (int q4=0;q4<4;q4++){
        float4 o;
        o.x = acc[r][q4*4+0]+cv[q4*4+0];
        o.y = acc[r][q4*4+1]+cv[q4*4+1];
        o.z = acc[r][q4*4+2]+cv[q4*4+2];
        o.w = acc[r][q4*4+3]+cv[q4*4+3];
        *(float4*)&out[(size_t)i*256 + ty*16 + q4*4] = o;
      }
    }
  }
}

extern "C" void kernel_launch(void* const* d_in, const int* in_sizes, int n_in,
                              void* d_out, int out_size, void* d_ws, size_t ws_size,
                              hipStream_t stream) {
  const float* h     = (const float*)d_in[0];
  const int*   esrc  = (const int*)d_in[1];
  const int*   edst  = (const int*)d_in[2];
  const float* W1    = (const float*)d_in[3];
  const float* b1    = (const float*)d_in[4];
  const float* W2    = (const float*)d_in[5];
  const float* b2    = (const float*)d_in[6];
  const float* gamma = (const float*)d_in[7];
  const float* beta  = (const float*)d_in[8];
  const float* eps1  = (const float*)d_in[9];
  int N = in_sizes[0] / IN_DIM;
  int E = in_sizes[1];
  float* out = (float*)d_out;

  char* ws = (char*)d_ws;
  size_t off = 0;
  auto alloc = [&](size_t bytes)->char* {
    char* p = ws + off; off = align256(off + bytes); return p;
  };
  int*   deg      = (int*)  alloc((size_t)N*4);
  int*   row_ptr  = (int*)  alloc(((size_t)N+1)*4);
  int*   cursor   = (int*)  alloc((size_t)N*4);
  int*   part     = (int*)  alloc(512*4);
  int*   partScan = (int*)  alloc(512*4);
  int*   eidx     = (int*)  alloc((size_t)E*4);
  float* S2       = (float*)alloc(128*128*4 + 128*4);   // + colsum tail
  float* colsum   = S2 + 128*128;
  float* qbuf     = (float*)alloc(256*4);
  float* sbuf     = (float*)alloc(256*4);
  float* cbuf     = (float*)alloc(256*4);
  float* Mm       = (float*)alloc(256*128*4);
  float* g        = (float*)alloc((size_t)N*128*4);
  (void)ws_size; (void)n_in; (void)out_size;

  hipMemsetAsync(deg, 0, (size_t)N*4, stream);
  hipMemsetAsync(S2, 0, 128*128*4 + 128*4, stream);

  int nblk = (N + 255)/256;   // 391 for N=100000 (must be <= 512)
  k_count<<<1024, 256, 0, stream>>>(edst, deg, E);
  k_scan1<<<nblk, 256, 0, stream>>>(deg, part, N);
  k_scan2<<<1, 512, 0, stream>>>(part, partScan, nblk, row_ptr, N, E);
  k_scan3<<<nblk, 256, 0, stream>>>(deg, partScan, row_ptr, cursor, N);
  k_fill<<<2048, 256, 0, stream>>>(esrc, edst, cursor, eidx, E);
  k_gather<<<(N+3)/4, 256, 0, stream>>>(h, row_ptr, eidx, eps1, g, N);
  k_gram<<<512, 256, 0, stream>>>(g, S2, colsum, N);
  k_quad<<<256, 128, 0, stream>>>(W1, S2, qbuf);
  k_stats2<<<1, 256, 0, stream>>>(W1, b1, W2, b2, gamma, beta, eps1, colsum, qbuf, cbuf ? sbuf : sbuf, cbuf, N);
  k_matM<<<256, 128, 0, stream>>>(W1, W2, sbuf, Mm);
  k_out<<<(N+63)/64, 256, 0, stream>>>(g, Mm, cbuf, out, N);
}